// Round 1
// baseline (6171.054 us; speedup 1.0000x reference)
//
#include <hip/hip_runtime.h>
#include <math.h>

// Archetipes RNN scan: T=256 sequential steps, M=16 modules, H=256, I=128.
// R8: single-hop synchronization — the data IS the flag.
// R7 post-mortem: 8.3 us/step with ~0.7 us VALU -> latency-bound on the
// two-hop chain: data store -> vmcnt(0) drain at bar -> RELEASE flag store
// (agent release also fences non-coherent L2) -> consumer flag poll ->
// separate data load -> stage -> 2nd bar.  >=3 serialized LLC round trips.
// Changes:
//  1. g_hy is u64: (tag<<32)|float_bits, tag = base + t + 1. Consumers poll
//     the 4 tagged words they need and break when all tags match: ONE LLC
//     hop per step, no flags, no release fence, no drain-before-flag.
//  2. hy_lds double-buffered (2x16 KB) -> ONE __syncthreads per step; the
//     publish store's ack drains at the NEXT iteration's barrier, fully
//     overlapped with the poll wait.
//  3. g_step[h] is now a per-launch epoch (bumped by T+1 at kernel end,
//     read only by block h itself) -> tags are monotone per address across
//     graph replays; stale packets from launch L-1 can never match launch
//     L's targets. First launch: globals zero-init, tag 0 never a target.
// Weights register/AGPR-resident (R3), conn-sparsity olist (R4), LDS
// out-buffering + single flush (R7) unchanged.

#define DT_C    0.042f
#define GAMMA_C 2.7f
#define EPS_C   4.7f

constexpr int M = 16, H = 256, I = 128, T = 256;
constexpr int NROW = M * H;   // 4096
constexpr int NBLK = 256;
constexpr int NTHR = 1024;    // 16 waves

typedef float f32x4 __attribute__((ext_vector_type(4)));
typedef unsigned long long u64;
typedef unsigned int u32;

// Slot s (s=0..T) = hy after s steps, layout [s][h][m], packet per value.
__device__ __align__(64) u64 g_hy[(size_t)(T + 1) * NROW];   // 8.4 MB
__device__ u32 g_step[NBLK];   // per-column launch epoch

__global__ __launch_bounds__(NTHR) void rnn_persistent(
    const float* __restrict__ x,      // T*I
    const float* __restrict__ wm,     // M*M*H*H
    const float* __restrict__ conn,   // M*M
    const float* __restrict__ mask,   // M
    const float* __restrict__ W_in,   // M*H*I
    const float* __restrict__ W_rec,  // M*H*H
    const float* __restrict__ bias,   // M*H
    float* __restrict__ out)          // T*M*2*H state_seq, then T*M*H fb_seq
{
  const int h    = blockIdx.x;
  const int tid  = threadIdx.x;
  const int m    = tid >> 6;      // wave = module
  const int lane = tid & 63;

  __shared__ float hy_lds[2][NROW];     // 32 KB double buffer, layout [m][h]
  __shared__ float outb_hz[T][M];       // 16 KB
  __shared__ float outb_fb[T][M];       // 16 KB
  __shared__ float s_c[M * M];
  __shared__ float s_scal[M];
  __shared__ int   s_olist[M][M];
  __shared__ float s_oc[M][M];
  __shared__ int   s_ocnt[M];
  __shared__ u32   s_base;

  if (tid == 0)
    s_base = __hip_atomic_load(&g_step[h], __ATOMIC_RELAXED, __HIP_MEMORY_SCOPE_AGENT);
  if (tid < M * M) s_c[tid] = conn[tid];
  __syncthreads();
  if (tid < M) {
    float s = 0.f; int cnt = 0;
    for (int o = 0; o < M; ++o) {
      float c = s_c[tid * M + o];
      s += c;
      if (c != 0.f) { s_olist[tid][cnt] = o; s_oc[tid][cnt] = c; ++cnt; }
    }
    for (int k = cnt; k < M; ++k) { s_olist[tid][k] = 0; s_oc[tid][k] = 0.f; }
    s_ocnt[tid] = cnt;
    s_scal[tid] = 1.0f / fmaxf(s, 1.0f);
  }
  __syncthreads();

  const int   row   = m * H + h;
  const float maskm = mask[m];
  const float biasv = bias[row];
  const float scal  = s_scal[m];
  const int   ocnt  = s_ocnt[m];
  const u32   base  = s_base;

  // ---- one-time: weights into registers (conn pre-applied) ----
  f32x4 wreg[M];
#pragma unroll
  for (int k = 0; k < M; ++k) {
    if (k < ocnt) {
      const int o = s_olist[m][k];
      const f32x4 wv = *reinterpret_cast<const f32x4*>(
          wm + ((size_t)(m * M + o) * H + h) * H + 4 * lane);
      wreg[k] = wv * s_oc[m][k];
    } else {
      wreg[k] = (f32x4)0.f;
    }
  }
  const f32x4  wrec = *reinterpret_cast<const f32x4*>(W_rec + (size_t)row * H + 4 * lane);
  const float2 win  = *reinterpret_cast<const float2*>(W_in + (size_t)row * I + 2 * lane);

  // ---- publish slot 0 = zeros, tagged base+1 (no flag, no barrier) ----
  if (tid < M) {
    const u64 pkt0 = ((u64)(base + 1u) << 32);   // hy = 0.0f
    __hip_atomic_store(&g_hy[(size_t)h * M + tid], pkt0,
                       __ATOMIC_RELAXED, __HIP_MEMORY_SCOPE_AGENT);
  }
  float hz = 0.f;

  // x[0] prefetch (per-lane slice; same for every wave)
  float2 xd = *reinterpret_cast<const float2*>(x + 2 * lane);

  const int hcol = tid >> 2;        // source column this thread stages
  const int moff = (tid & 3) * 4;   // my 4 modules of that column
  int buf = 0;

  for (int t = 0; t < T; ++t) {
    // ---- single-hop poll + stage: tags embedded in the data words ----
    {
      const u32 tgt = base + (u32)t + 1u;
      const u64* src = g_hy + (size_t)t * NROW + (size_t)hcol * M + moff;
      u64 a0, a1, a2, a3;
      for (;;) {
        a0 = __hip_atomic_load(src + 0, __ATOMIC_RELAXED, __HIP_MEMORY_SCOPE_AGENT);
        a1 = __hip_atomic_load(src + 1, __ATOMIC_RELAXED, __HIP_MEMORY_SCOPE_AGENT);
        a2 = __hip_atomic_load(src + 2, __ATOMIC_RELAXED, __HIP_MEMORY_SCOPE_AGENT);
        a3 = __hip_atomic_load(src + 3, __ATOMIC_RELAXED, __HIP_MEMORY_SCOPE_AGENT);
        if ((((u32)(a0 >> 32)) == tgt) & (((u32)(a1 >> 32)) == tgt) &
            (((u32)(a2 >> 32)) == tgt) & (((u32)(a3 >> 32)) == tgt))
          break;
        __builtin_amdgcn_s_sleep(1);
      }
      float* dst = &hy_lds[buf][0];
      dst[(moff + 0) * H + hcol] = __uint_as_float((u32)a0);
      dst[(moff + 1) * H + hcol] = __uint_as_float((u32)a1);
      dst[(moff + 2) * H + hcol] = __uint_as_float((u32)a2);
      dst[(moff + 3) * H + hcol] = __uint_as_float((u32)a3);
    }
    __syncthreads();   // ONLY barrier per step; prev publish ack drains here

    // input term (xd prefetched last iteration)
    float acc_o = win.x * (maskm * xd.x);
    acc_o = fmaf(win.y, maskm * xd.y, acc_o);
    // recurrent term
    {
      const f32x4 hp = *reinterpret_cast<const f32x4*>(&hy_lds[buf][m * H + 4 * lane]);
      acc_o = fmaf(wrec.x, hp.x, acc_o);
      acc_o = fmaf(wrec.y, hp.y, acc_o);
      acc_o = fmaf(wrec.z, hp.z, acc_o);
      acc_o = fmaf(wrec.w, hp.w, acc_o);
    }
    // feedback: register weights x LDS hy fragments
    float acc_fb = 0.f;
#pragma unroll
    for (int k = 0; k < M; ++k) {
      if (k < ocnt) {
        const int o = s_olist[m][k];
        const f32x4 hp = *reinterpret_cast<const f32x4*>(&hy_lds[buf][o * H + 4 * lane]);
        float po = wreg[k].x * hp.x;
        po = fmaf(wreg[k].y, hp.y, po);
        po = fmaf(wreg[k].z, hp.z, po);
        po = fmaf(wreg[k].w, hp.w, po);
        acc_fb += po;
      }
    }

    // wave-wide butterfly reduce
    for (int off = 32; off > 0; off >>= 1) {
      acc_fb += __shfl_xor(acc_fb, off);
      acc_o  += __shfl_xor(acc_o,  off);
    }

    if (lane == 0) {
      const float fb   = scal * acc_fb;
      const float hy_p = hy_lds[buf][row];
      const float pre  = acc_o + biasv + fb;
      const float hz_n = hz + DT_C * (tanhf(pre) - GAMMA_C * hy_p - EPS_C * hz);
      const float hy_n = hy_p + DT_C * hz_n;
      hz = hz_n;
      // publish hy_t into slot t+1 with tag tgt+1: the packet is the flag
      const u64 pkt = ((u64)(base + (u32)t + 2u) << 32) |
                      (u64)__float_as_uint(hy_n);
      __hip_atomic_store(&g_hy[(size_t)(t + 1) * NROW + (size_t)h * M + m], pkt,
                         __ATOMIC_RELAXED, __HIP_MEMORY_SCOPE_AGENT);
      // buffer hz/fb in LDS; flushed once after the loop
      outb_hz[t][m] = hz_n;
      outb_fb[t][m] = fb;
    }

    if (t + 1 < T)
      xd = *reinterpret_cast<const float2*>(x + (size_t)(t + 1) * I + 2 * lane);
    buf ^= 1;
  }

  __syncthreads();   // outb_* visible; final publishes drained (vmcnt(0))

  // ---- one-time flush: hy from own g_hy slots, hz/fb from LDS ----
  const size_t fb_base = (size_t)T * M * 2 * H;
  for (int i = tid; i < T * M; i += NTHR) {
    const int t  = i >> 4;
    const int mm = i & 15;
    const u64 q = __hip_atomic_load(
        &g_hy[(size_t)(t + 1) * NROW + (size_t)h * M + mm],
        __ATOMIC_RELAXED, __HIP_MEMORY_SCOPE_AGENT);
    const float hyv = __uint_as_float((u32)q);
    const size_t so = (size_t)t * (M * 2 * H) + (size_t)mm * (2 * H);
    out[so + h]     = hyv;
    out[so + H + h] = outb_hz[t][mm];
    out[fb_base + (size_t)t * (M * H) + (size_t)mm * H + h] = outb_fb[t][mm];
  }

  // epoch bump for next launch/replay (read only by this block)
  if (tid == 0)
    __hip_atomic_store(&g_step[h], base + (u32)(T + 1),
                       __ATOMIC_RELAXED, __HIP_MEMORY_SCOPE_AGENT);
}

extern "C" void kernel_launch(void* const* d_in, const int* in_sizes, int n_in,
                              void* d_out, int out_size, void* d_ws, size_t ws_size,
                              hipStream_t stream) {
  const float* x     = (const float*)d_in[0];
  const float* wm    = (const float*)d_in[1];
  const float* conn  = (const float*)d_in[2];
  const float* mask  = (const float*)d_in[3];
  const float* W_in  = (const float*)d_in[4];
  const float* W_rec = (const float*)d_in[5];
  const float* bias  = (const float*)d_in[6];

  rnn_persistent<<<NBLK, NTHR, 0, stream>>>(
      x, wm, conn, mask, W_in, W_rec, bias, (float*)d_out);
}

// Round 2
// 1862.694 us; speedup vs baseline: 3.3130x; 3.3130x over previous
//
#include <hip/hip_runtime.h>
#include <math.h>

// Archetipes RNN scan: T=256 sequential steps, M=16 modules, H=256, I=128.
// R9: hierarchical fence-free sync — tagged data + aggregator beacon.
// R8 post-mortem: tags-in-data was correct but every thread polled 4 STRIDED
// u64s -> ~128 line-requests/wave/iter -> ~512K LLC transactions per poll
// round chip-wide -> coherence point saturated, publishes queued behind
// polls (23.9 us/step). Transaction count per poll iteration is the
// first-order quantity with 262K spinning threads.
// Changes:
//  1. Flat packet layout g_hy[slot][h*16+m]: producer block h's 16 packets
//     contiguous (2 lines); consumer staging loads dense per instruction.
//  2. 16 aggregator waves (wave 0 of blocks 0..15) poll their 256 watched
//     packets (dense: 8 lines/instr) and publish a 16-replica BEACON u32.
//     Chip-wide poll cost: ~512 line-req/iter (1000x less than R8).
//  3. Consumers poll ONE beacon line (16 dwords, 1 coalesced transaction
//     per wave per iter), replica spread by (h+m)&15.
//  4. Staging happens ONCE per step after the beacon passes: thread tid
//     loads packets tid+1024k (consecutive per instruction, 8 lines).
//  5. No release fences, no drain-before-flag. Ordering: packets reach LLC
//     before beacon store (control dep), beacon seen => packets readable
//     (LLC write serialization). asm memory barriers pin compiler order of
//     relaxed atomics. Double-buffered LDS -> ONE __syncthreads per step.
//  6. g_epoch (single u32) bumped by block 0 at end -> monotone tags across
//     graph replays; stale packets/beacons always compare < first target.
// Weights register-resident (R3), conn-sparsity olist (R4), LDS
// out-buffering + single flush (R7) unchanged.

#define DT_C    0.042f
#define GAMMA_C 2.7f
#define EPS_C   4.7f

constexpr int M = 16, H = 256, I = 128, T = 256;
constexpr int NROW = M * H;   // 4096 packets per slot
constexpr int NBLK = 256;
constexpr int NTHR = 1024;    // 16 waves
constexpr int NAGG = 16;      // aggregator waves (wave 0 of blocks 0..15)
constexpr int NREP = 16;      // beacon replica lines

typedef float f32x4 __attribute__((ext_vector_type(4)));
typedef unsigned long long u64;
typedef unsigned int u32;

// Slot s (s=0..T) = hy after s steps. Packet = (tag<<32)|float_bits,
// tag = epoch + s + 1. Flat index p = h*16 + m.
__device__ __align__(64) u64 g_hy[(size_t)(T + 1) * NROW];   // 8.4 MB
__device__ __align__(64) u32 g_beacon[NREP][NAGG];           // 16 x 64 B
__device__ u32 g_epoch;

__global__ __launch_bounds__(NTHR) void rnn_persistent(
    const float* __restrict__ x,      // T*I
    const float* __restrict__ wm,     // M*M*H*H
    const float* __restrict__ conn,   // M*M
    const float* __restrict__ mask,   // M
    const float* __restrict__ W_in,   // M*H*I
    const float* __restrict__ W_rec,  // M*H*H
    const float* __restrict__ bias,   // M*H
    float* __restrict__ out)          // T*M*2*H state_seq, then T*M*H fb_seq
{
  const int h    = blockIdx.x;
  const int tid  = threadIdx.x;
  const int m    = tid >> 6;      // wave = module
  const int lane = tid & 63;

  __shared__ float hy_lds[2][NROW];     // 32 KB double buffer, layout [m][h]
  __shared__ float outb_hz[T][M];       // 16 KB
  __shared__ float outb_fb[T][M];       // 16 KB
  __shared__ float s_c[M * M];
  __shared__ float s_scal[M];
  __shared__ int   s_olist[M][M];
  __shared__ float s_oc[M][M];
  __shared__ int   s_ocnt[M];
  __shared__ u32   s_base;

  if (tid == 0)
    s_base = __hip_atomic_load(&g_epoch, __ATOMIC_RELAXED, __HIP_MEMORY_SCOPE_AGENT);
  if (tid < M * M) s_c[tid] = conn[tid];
  __syncthreads();

  // ---- publish slot 0 = zeros ASAP (before heavy weight loads) ----
  const u32 base = s_base;
  if (tid < M) {
    const u64 pkt0 = ((u64)(base + 1u) << 32);   // hy = 0.0f, tag = base+1
    __hip_atomic_store(&g_hy[(size_t)h * M + tid], pkt0,
                       __ATOMIC_RELAXED, __HIP_MEMORY_SCOPE_AGENT);
  }

  if (tid < M) {
    float s = 0.f; int cnt = 0;
    for (int o = 0; o < M; ++o) {
      float c = s_c[tid * M + o];
      s += c;
      if (c != 0.f) { s_olist[tid][cnt] = o; s_oc[tid][cnt] = c; ++cnt; }
    }
    for (int k = cnt; k < M; ++k) { s_olist[tid][k] = 0; s_oc[tid][k] = 0.f; }
    s_ocnt[tid] = cnt;
    s_scal[tid] = 1.0f / fmaxf(s, 1.0f);
  }
  __syncthreads();

  const int   row   = m * H + h;
  const float maskm = mask[m];
  const float biasv = bias[row];
  const float scal  = s_scal[m];
  const int   ocnt  = s_ocnt[m];

  // ---- one-time: weights into registers (conn pre-applied) ----
  f32x4 wreg[M];
#pragma unroll
  for (int k = 0; k < M; ++k) {
    if (k < ocnt) {
      const int o = s_olist[m][k];
      const f32x4 wv = *reinterpret_cast<const f32x4*>(
          wm + ((size_t)(m * M + o) * H + h) * H + 4 * lane);
      wreg[k] = wv * s_oc[m][k];
    } else {
      wreg[k] = (f32x4)0.f;
    }
  }
  const f32x4  wrec = *reinterpret_cast<const f32x4*>(W_rec + (size_t)row * H + 4 * lane);
  const float2 win  = *reinterpret_cast<const float2*>(W_in + (size_t)row * I + 2 * lane);

  float hz = 0.f;
  // x[0] prefetch (per-lane slice; same for every wave)
  float2 xd = *reinterpret_cast<const float2*>(x + 2 * lane);

  const bool is_agg = (h < NAGG) && (m == 0);   // wave 0 of blocks 0..15
  const int  mcol   = (tid & 15) * H;           // staging LDS column base
  const int  hrow   = tid >> 4;                 // staging LDS row
  int buf = 0;

  for (int t = 0; t < T; ++t) {
    const u32 tgt = base + (u32)t + 1u;

    // ---- aggregator: watch 256 packets (dense), then publish beacon ----
    if (is_agg) {
      const u64* wp = g_hy + (size_t)t * NROW + (size_t)h * 256 + lane;
      for (;;) {
        const u64 a0 = __hip_atomic_load(wp,       __ATOMIC_RELAXED, __HIP_MEMORY_SCOPE_AGENT);
        const u64 a1 = __hip_atomic_load(wp + 64,  __ATOMIC_RELAXED, __HIP_MEMORY_SCOPE_AGENT);
        const u64 a2 = __hip_atomic_load(wp + 128, __ATOMIC_RELAXED, __HIP_MEMORY_SCOPE_AGENT);
        const u64 a3 = __hip_atomic_load(wp + 192, __ATOMIC_RELAXED, __HIP_MEMORY_SCOPE_AGENT);
        const bool ok = (((u32)(a0 >> 32)) >= tgt) & (((u32)(a1 >> 32)) >= tgt) &
                        (((u32)(a2 >> 32)) >= tgt) & (((u32)(a3 >> 32)) >= tgt);
        if (__all(ok)) break;
        __builtin_amdgcn_s_sleep(1);
      }
      if (lane < NREP)
        __hip_atomic_store(&g_beacon[lane][h], tgt,
                           __ATOMIC_RELAXED, __HIP_MEMORY_SCOPE_AGENT);
      asm volatile("" ::: "memory");
    }

    // ---- consumer: poll ONE replicated beacon line (coalesced) ----
    {
      const u32* bp = &g_beacon[(h + m) & (NREP - 1)][lane & 15];
      while (!__all(__hip_atomic_load(bp, __ATOMIC_RELAXED,
                                      __HIP_MEMORY_SCOPE_AGENT) >= tgt))
        __builtin_amdgcn_s_sleep(1);
      asm volatile("" ::: "memory");
    }

    // ---- stage ONCE: thread tid loads packets tid+1024k (dense) ----
    {
      const u64* src = g_hy + (size_t)t * NROW + tid;
      const u64 a0 = __hip_atomic_load(src,        __ATOMIC_RELAXED, __HIP_MEMORY_SCOPE_AGENT);
      const u64 a1 = __hip_atomic_load(src + 1024, __ATOMIC_RELAXED, __HIP_MEMORY_SCOPE_AGENT);
      const u64 a2 = __hip_atomic_load(src + 2048, __ATOMIC_RELAXED, __HIP_MEMORY_SCOPE_AGENT);
      const u64 a3 = __hip_atomic_load(src + 3072, __ATOMIC_RELAXED, __HIP_MEMORY_SCOPE_AGENT);
      float* dst = &hy_lds[buf][0];
      // packet p = tid + 1024k: module = p&15 (== tid&15), column = p>>4
      dst[mcol + hrow      ] = __uint_as_float((u32)a0);
      dst[mcol + hrow +  64] = __uint_as_float((u32)a1);
      dst[mcol + hrow + 128] = __uint_as_float((u32)a2);
      dst[mcol + hrow + 192] = __uint_as_float((u32)a3);
    }
    __syncthreads();   // ONLY barrier per step; prev publish ack drains here

    // input term (xd prefetched last iteration)
    float acc_o = win.x * (maskm * xd.x);
    acc_o = fmaf(win.y, maskm * xd.y, acc_o);
    // recurrent term
    {
      const f32x4 hp = *reinterpret_cast<const f32x4*>(&hy_lds[buf][m * H + 4 * lane]);
      acc_o = fmaf(wrec.x, hp.x, acc_o);
      acc_o = fmaf(wrec.y, hp.y, acc_o);
      acc_o = fmaf(wrec.z, hp.z, acc_o);
      acc_o = fmaf(wrec.w, hp.w, acc_o);
    }
    // feedback: register weights x LDS hy fragments
    float acc_fb = 0.f;
#pragma unroll
    for (int k = 0; k < M; ++k) {
      if (k < ocnt) {
        const int o = s_olist[m][k];
        const f32x4 hp = *reinterpret_cast<const f32x4*>(&hy_lds[buf][o * H + 4 * lane]);
        float po = wreg[k].x * hp.x;
        po = fmaf(wreg[k].y, hp.y, po);
        po = fmaf(wreg[k].z, hp.z, po);
        po = fmaf(wreg[k].w, hp.w, po);
        acc_fb += po;
      }
    }

    // wave-wide butterfly reduce
    for (int off = 32; off > 0; off >>= 1) {
      acc_fb += __shfl_xor(acc_fb, off);
      acc_o  += __shfl_xor(acc_o,  off);
    }

    if (lane == 0) {
      const float fb   = scal * acc_fb;
      const float hy_p = hy_lds[buf][row];
      const float pre  = acc_o + biasv + fb;
      const float hz_n = hz + DT_C * (tanhf(pre) - GAMMA_C * hy_p - EPS_C * hz);
      const float hy_n = hy_p + DT_C * hz_n;
      hz = hz_n;
      // publish hy_t into slot t+1 (tag = tgt+1): the packet is the flag
      const u64 pkt = ((u64)(tgt + 1u) << 32) | (u64)__float_as_uint(hy_n);
      __hip_atomic_store(&g_hy[(size_t)(t + 1) * NROW + (size_t)h * M + m], pkt,
                         __ATOMIC_RELAXED, __HIP_MEMORY_SCOPE_AGENT);
      // buffer hz/fb in LDS; flushed once after the loop
      outb_hz[t][m] = hz_n;
      outb_fb[t][m] = fb;
    }

    if (t + 1 < T)
      xd = *reinterpret_cast<const float2*>(x + (size_t)(t + 1) * I + 2 * lane);
    buf ^= 1;
  }

  __syncthreads();   // outb_* visible; final publishes drained (vmcnt(0))

  // ---- one-time flush: hy from own g_hy slots, hz/fb from LDS ----
  const size_t fb_base = (size_t)T * M * 2 * H;
  for (int i = tid; i < T * M; i += NTHR) {
    const int t  = i >> 4;
    const int mm = i & 15;
    const u64 q = __hip_atomic_load(
        &g_hy[(size_t)(t + 1) * NROW + (size_t)h * M + mm],
        __ATOMIC_RELAXED, __HIP_MEMORY_SCOPE_AGENT);
    const float hyv = __uint_as_float((u32)q);
    const size_t so = (size_t)t * (M * 2 * H) + (size_t)mm * (2 * H);
    out[so + h]     = hyv;
    out[so + H + h] = outb_hz[t][mm];
    out[fb_base + (size_t)t * (M * H) + (size_t)mm * H + h] = outb_fb[t][mm];
  }

  // epoch bump for next launch/replay: strictly above every tag used here
  if (h == 0 && tid == 0)
    __hip_atomic_store(&g_epoch, base + (u32)(T + 2),
                       __ATOMIC_RELAXED, __HIP_MEMORY_SCOPE_AGENT);
}

extern "C" void kernel_launch(void* const* d_in, const int* in_sizes, int n_in,
                              void* d_out, int out_size, void* d_ws, size_t ws_size,
                              hipStream_t stream) {
  const float* x     = (const float*)d_in[0];
  const float* wm    = (const float*)d_in[1];
  const float* conn  = (const float*)d_in[2];
  const float* mask  = (const float*)d_in[3];
  const float* W_in  = (const float*)d_in[4];
  const float* W_rec = (const float*)d_in[5];
  const float* bias  = (const float*)d_in[6];

  rnn_persistent<<<NBLK, NTHR, 0, stream>>>(
      x, wm, conn, mask, W_in, W_rec, bias, (float*)d_out);
}